// Round 2
// baseline (259.004 us; speedup 1.0000x reference)
//
#include <hip/hip_runtime.h>

typedef unsigned short u16;
typedef unsigned int   u32;
typedef __bf16 bf16x8 __attribute__((ext_vector_type(8)));
typedef float  f32x4  __attribute__((ext_vector_type(4)));
typedef unsigned short u16x8 __attribute__((ext_vector_type(8)));
typedef unsigned short u16x4 __attribute__((ext_vector_type(4)));

#define SEQ 2048
#define DM  1024
#define TOKS 8388608  // 4*2048*1024 elements
#define SCLQ 0.18033688f  // log2(e)/8, folded into Q projection

__device__ __forceinline__ float bf2f(u16 u) {
    u32 i = ((u32)u) << 16;
    float f; __builtin_memcpy(&f, &i, 4); return f;
}
__device__ __forceinline__ u16 f2bf(float f) {
    u32 i; __builtin_memcpy(&i, &f, 4);
    return (u16)((i + 0x7FFFu + ((i >> 16) & 1u)) >> 16);  // RNE
}
__device__ __forceinline__ bf16x8 ld8(const u16* p) {
    return __builtin_bit_cast(bf16x8, *(const u16x8*)p);
}
#define GLD16(src, dst) __builtin_amdgcn_global_load_lds( \
    (const __attribute__((address_space(1))) void*)(src), \
    (__attribute__((address_space(3))) void*)(dst), 16, 0, 0)

// compiler+machine fence around a raw barrier (no vmcnt drain)
#define SBAR() do { asm volatile("" ::: "memory"); __builtin_amdgcn_sched_barrier(0); \
    __builtin_amdgcn_s_barrier(); __builtin_amdgcn_sched_barrier(0); asm volatile("" ::: "memory"); } while (0)
#define WVM(n) asm volatile("s_waitcnt vmcnt(" #n ")" ::: "memory")

// ---------------- dtype detection: bf16 vs fp32 inputs ----------------
__global__ __launch_bounds__(64) void detect_k(const u32* __restrict__ x, int* __restrict__ flag) {
    const int lane = threadIdx.x;
    u32 w = x[lane];
    int e0 = (int)((w >> 7) & 0xFFu);
    int cnt = (e0 >= 100 && e0 <= 140) ? 1 : 0;
#pragma unroll
    for (int off = 32; off; off >>= 1) cnt += __shfl_xor(cnt, off);
    if (lane == 0) *flag = (cnt < 32) ? 1 : 0;   // 1 = fp32 inputs
}

// ---------------- convert weights/vectors to bf16 in ws ----------------
__global__ __launch_bounds__(256) void convert_k(const void* s0, const void* s1, const void* s2, const void* s3,
                                                 const void* v0, const void* v1, const void* v2, const void* v3,
                                                 const void* v4, const void* v5,
                                                 u16* __restrict__ dstW, u16* __restrict__ dstV,
                                                 const int* __restrict__ flagp) {
    const int y = blockIdx.y, tid = threadIdx.x;
    const int fp32m = *flagp;
    const void* src; u16* dst; size_t off;
    if (y < 4) {
        src = (y == 0) ? s0 : (y == 1) ? s1 : (y == 2) ? s2 : s3;
        dst = dstW + (size_t)y * 1048576;
        off = (size_t)blockIdx.x * 1024 + tid * 4;
    } else {
        const int i = blockIdx.x;
        if (i >= 6) return;
        src = (i == 0) ? v0 : (i == 1) ? v1 : (i == 2) ? v2 : (i == 3) ? v3 : (i == 4) ? v4 : v5;
        dst = dstV + (size_t)i * 1024;
        off = (size_t)tid * 4;
    }
    u16x4 o;
    if (fp32m) {
        const float* f = (const float*)src + off;
#pragma unroll
        for (int j = 0; j < 4; ++j) o[j] = f2bf(f[j]);
    } else {
        o = *(const u16x4*)((const u16*)src + off);
    }
    *(u16x4*)(dst + off) = o;
}

// ---------------- LayerNorm: one block per token row ----------------
__global__ __launch_bounds__(256) void ln_k(const void* __restrict__ xv,
                                            const u16* __restrict__ g,
                                            const u16* __restrict__ b,
                                            u16* __restrict__ xn,
                                            const int* __restrict__ flagp) {
    const int row = blockIdx.x, tid = threadIdx.x;
    const int fp32m = *flagp;
    float f[4], s1 = 0.f, s2 = 0.f;
    if (fp32m) {
        f32x4 v = *(const f32x4*)((const float*)xv + (size_t)row * DM + tid * 4);
#pragma unroll
        for (int j = 0; j < 4; ++j) f[j] = v[j];
    } else {
        u16x4 v = *(const u16x4*)((const u16*)xv + (size_t)row * DM + tid * 4);
#pragma unroll
        for (int j = 0; j < 4; ++j) f[j] = bf2f(v[j]);
    }
#pragma unroll
    for (int j = 0; j < 4; ++j) { s1 += f[j]; s2 += f[j] * f[j]; }
#pragma unroll
    for (int off = 32; off; off >>= 1) { s1 += __shfl_xor(s1, off); s2 += __shfl_xor(s2, off); }
    __shared__ float red[8];
    const int wave = tid >> 6, lane = tid & 63;
    if (lane == 0) { red[wave] = s1; red[4 + wave] = s2; }
    __syncthreads();
    s1 = red[0] + red[1] + red[2] + red[3];
    s2 = red[4] + red[5] + red[6] + red[7];
    const float mu = s1 * (1.f / DM);
    const float var = s2 * (1.f / DM) - mu * mu;
    const float rs = rsqrtf(var + 1e-5f);
    u16x4 gv = *(const u16x4*)(g + tid * 4);
    u16x4 bv = *(const u16x4*)(b + tid * 4);
    u16x4 o;
#pragma unroll
    for (int j = 0; j < 4; ++j) o[j] = f2bf((f[j] - mu) * rs * bf2f(gv[j]) + bf2f(bv[j]));
    *(u16x4*)(xn + (size_t)row * DM + tid * 4) = o;
}

// ============ QKV GEMM: 256x256 tile, 4-phase/K-tile deep pipeline ============
// 8 waves (2M x 4N), per-wave 128x64 output (43.7 FLOP per LDS byte read).
// LDS: 2 buffers x (A[256][64] + B[256][64]) bf16 = 128 KiB, chunk-XOR swizzle
// (chunk ^= row&7) on both sides: pre-swizzled global source for the linear
// global_load_lds dest + swizzled ds_read offsets.
// Half-tiles per K-tile (16 KB = 2 GLD16/wave each), prefetched one per phase:
//   H0 = A rows {0-63,128-191}  (every wave's Mlo)
//   H1 = B col-stripes {s*64+0..31}   (every wave's Nlo)
//   H2 = A rows {64-127,192-255} (Mhi)
//   H3 = B col-stripes {s*64+32..63} (Nhi)
// Phases per K-tile: P1=Q(Mlo,Nlo) reads H0+H1 | P2=Q(Mhi,Nlo) reads H2 |
// P3=Q(Mhi,Nhi) reads H3 | P4=Q(Mlo,Nhi) reads nothing.  vmcnt(4) at P1-P3
// (steady state: 6-8 loads in flight, never drained below 4).  setprio(1)
// around each 16-MFMA quadrant.  K accumulation order identical to the old
// 32-step loop (bit-exact outputs).
__global__ __launch_bounds__(512, 2) void gemm_qkv_k(const u16* __restrict__ xn, const u16* __restrict__ Wc,
                                                     const u16* __restrict__ Vc,
                                                     u16* __restrict__ Q, u16* __restrict__ K, u16* __restrict__ Vt) {
    __shared__ alignas(16) u16 lds[65536];   // 131072 B
    const int tid = threadIdx.x;
    const int w = tid >> 6, lane = tid & 63;
    const int l4 = lane & 15, q4 = lane >> 4;
    const int bm = blockIdx.x, bn = blockIdx.y;
    const int wm0 = (w >> 2) * 128, wn = (w & 3) * 64;

    // staging source (pre-swizzled 16B chunk; rows in groups of 8 so row&7==srow)
    const int srow = lane >> 3, schk = (lane & 7) ^ srow;
    const u16* aS = xn + ((size_t)(bm * 256) + srow) * DM + schk * 8;
    const u16* bS = Wc + ((size_t)(bn * 256) + srow) * DM + schk * 8;
    const int bg0 = (w >> 1) * 64 + (w & 1) * 16;   // B H1 group base (n-space)

    auto STG = [&](int h, int kt, int bufb) {
        const size_t kk = (size_t)kt * 64;
        u16* ld0 = lds + bufb * 32768;
        if (h == 0) {
            GLD16(aS + (size_t)(8 * w) * DM + kk,        ld0 + (8 * w) * 64);
            GLD16(aS + (size_t)(128 + 8 * w) * DM + kk,  ld0 + (128 + 8 * w) * 64);
        } else if (h == 2) {
            GLD16(aS + (size_t)(64 + 8 * w) * DM + kk,   ld0 + (64 + 8 * w) * 64);
            GLD16(aS + (size_t)(192 + 8 * w) * DM + kk,  ld0 + (192 + 8 * w) * 64);
        } else {
            const int b0 = bg0 + ((h == 3) ? 32 : 0);
            GLD16(bS + (size_t)b0 * DM + kk,             ld0 + 16384 + b0 * 64);
            GLD16(bS + (size_t)(b0 + 8) * DM + kk,       ld0 + 16384 + (b0 + 8) * 64);
        }
    };

    // swizzled read offsets (u16 units): row*64 + ((chunk ^ (row&7))<<3)
    const int swz0 = (q4 ^ (l4 & 7)) << 3;        // k-slice 0: logical chunk q4
    const int swz1 = ((4 + q4) ^ (l4 & 7)) << 3;  // k-slice 1: logical chunk 4+q4
    const int arow = (wm0 + l4) * 64;
    const int brow = 16384 + (wn + l4) * 64;

    f32x4 acc[8][4] = {};
    bf16x8 afLo[4][2], afHi[4][2], bfr[2][2];

    STG(0, 0, 0); STG(1, 0, 0); STG(2, 0, 0); STG(3, 0, 0);   // 8 loads in flight

#pragma unroll
    for (int kt = 0; kt < 16; ++kt) {
        const int buf = kt & 1, nxt = buf ^ 1;
        const u16* bp = lds + buf * 32768;
        const bool pf = (kt < 15);
        // ---- P1: quadrant (Mlo, Nlo); needs H0 (A-lo) + H1 (B-nlo) ----
        WVM(4); SBAR();
        if (pf) STG(0, kt + 1, nxt);
#pragma unroll
        for (int mt = 0; mt < 4; ++mt) {
            afLo[mt][0] = ld8(bp + arow + mt * 1024 + swz0);
            afLo[mt][1] = ld8(bp + arow + mt * 1024 + swz1);
        }
#pragma unroll
        for (int nt = 0; nt < 2; ++nt) {
            bfr[nt][0] = ld8(bp + brow + nt * 1024 + swz0);
            bfr[nt][1] = ld8(bp + brow + nt * 1024 + swz1);
        }
        __builtin_amdgcn_s_setprio(1);
#pragma unroll
        for (int mt = 0; mt < 4; ++mt)
#pragma unroll
            for (int nt = 0; nt < 2; ++nt) {
                acc[mt][nt] = __builtin_amdgcn_mfma_f32_16x16x32_bf16(afLo[mt][0], bfr[nt][0], acc[mt][nt], 0, 0, 0);
                acc[mt][nt] = __builtin_amdgcn_mfma_f32_16x16x32_bf16(afLo[mt][1], bfr[nt][1], acc[mt][nt], 0, 0, 0);
            }
        __builtin_amdgcn_s_setprio(0);
        // ---- P2: quadrant (Mhi, Nlo); needs H2 (A-hi); B-nlo kept ----
        if (pf) { WVM(4); } else { WVM(2); }
        SBAR();
        if (pf) STG(1, kt + 1, nxt);
#pragma unroll
        for (int mt = 0; mt < 4; ++mt) {
            afHi[mt][0] = ld8(bp + arow + (mt + 4) * 1024 + swz0);
            afHi[mt][1] = ld8(bp + arow + (mt + 4) * 1024 + swz1);
        }
        __builtin_amdgcn_s_setprio(1);
#pragma unroll
        for (int mt = 0; mt < 4; ++mt)
#pragma unroll
            for (int nt = 0; nt < 2; ++nt) {
                acc[mt + 4][nt] = __builtin_amdgcn_mfma_f32_16x16x32_bf16(afHi[mt][0], bfr[nt][0], acc[mt + 4][nt], 0, 0, 0);
                acc[mt + 4][nt] = __builtin_amdgcn_mfma_f32_16x16x32_bf16(afHi[mt][1], bfr[nt][1], acc[mt + 4][nt], 0, 0, 0);
            }
        __builtin_amdgcn_s_setprio(0);
        // ---- P3: quadrant (Mhi, Nhi); needs H3 (B-nhi); A-hi kept ----
        if (pf) { WVM(4); } else { WVM(0); }
        SBAR();
        if (pf) STG(2, kt + 1, nxt);
#pragma unroll
        for (int nt = 0; nt < 2; ++nt) {
            bfr[nt][0] = ld8(bp + brow + (nt + 2) * 1024 + swz0);
            bfr[nt][1] = ld8(bp + brow + (nt + 2) * 1024 + swz1);
        }
        __builtin_amdgcn_s_setprio(1);
#pragma unroll
        for (int mt = 0; mt < 4; ++mt)
#pragma unroll
            for (int nt = 0; nt < 2; ++nt) {
                acc[mt + 4][nt + 2] = __builtin_amdgcn_mfma_f32_16x16x32_bf16(afHi[mt][0], bfr[nt][0], acc[mt + 4][nt + 2], 0, 0, 0);
                acc[mt + 4][nt + 2] = __builtin_amdgcn_mfma_f32_16x16x32_bf16(afHi[mt][1], bfr[nt][1], acc[mt + 4][nt + 2], 0, 0, 0);
            }
        __builtin_amdgcn_s_setprio(0);
        // ---- P4: quadrant (Mlo, Nhi); everything already in registers ----
        SBAR();
        if (pf) STG(3, kt + 1, nxt);
        __builtin_amdgcn_s_setprio(1);
#pragma unroll
        for (int mt = 0; mt < 4; ++mt)
#pragma unroll
            for (int nt = 0; nt < 2; ++nt) {
                acc[mt][nt + 2] = __builtin_amdgcn_mfma_f32_16x16x32_bf16(afLo[mt][0], bfr[nt][0], acc[mt][nt + 2], 0, 0, 0);
                acc[mt][nt + 2] = __builtin_amdgcn_mfma_f32_16x16x32_bf16(afLo[mt][1], bfr[nt][1], acc[mt][nt + 2], 0, 0, 0);
            }
        __builtin_amdgcn_s_setprio(0);
    }

    // ---- epilogue: bn covers 256 cols of the 3072-wide fused QKV output ----
    const int whichB = bn >> 2;                    // 0:Q 1:K 2:V (block-uniform)
    const int cb = (bn & 3) * 256 + wn;
    u16* outp = (whichB == 0) ? Q : (whichB == 1) ? K : Vt;
    const float scl = (whichB == 0) ? SCLQ : 1.0f;
#pragma unroll
    for (int nt = 0; nt < 4; ++nt) {
        const int cc = cb + nt * 16 + l4;
        const float bs = bf2f(Vc[whichB * 1024 + cc]);
#pragma unroll
        for (int mt = 0; mt < 8; ++mt) {
            const int row0 = bm * 256 + wm0 + mt * 16 + q4 * 4;
            if (whichB < 2) {
#pragma unroll
                for (int r = 0; r < 4; ++r)
                    outp[(size_t)(row0 + r) * DM + cc] = f2bf((acc[mt][nt][r] + bs) * scl);
            } else {
                const int nb = row0 >> 11, s0 = row0 & 2047;
                u16x4 pk;
#pragma unroll
                for (int r = 0; r < 4; ++r) pk[r] = f2bf(acc[mt][nt][r] + bs);
                *(u16x4*)(outp + ((size_t)(nb * 1024 + cc)) * SEQ + s0) = pk;
            }
        }
    }
}

// ========== out-projection: verified Round-1 256x128 3-buffer core ==========
#define LDS_U16 73728   // 3 * 24576 u16 = 147456 B

__device__ __forceinline__ void wait_vm12() { asm volatile("s_waitcnt vmcnt(12)" ::: "memory"); }
__device__ __forceinline__ void wait_vm6()  { asm volatile("s_waitcnt vmcnt(6)"  ::: "memory"); }
__device__ __forceinline__ void wait_vm0()  { asm volatile("s_waitcnt vmcnt(0)"  ::: "memory"); }

__device__ __forceinline__ void gemm256x128_out(u16* lds,
                                                const u16* __restrict__ A,
                                                const u16* __restrict__ W,
                                                const u16* __restrict__ bias,
                                                u16* __restrict__ o0,
                                                int fp32m) {
    const int tid = threadIdx.x;
    const int w = tid >> 6, lane = tid & 63;
    const int l4 = lane & 15, q4 = lane >> 4;
    const int bm = blockIdx.x, bn = blockIdx.y;
    const int wm = (w >> 1) * 64, wn = (w & 1) * 64;

    const int srow = lane >> 3;
    const int schk = (lane & 7) ^ srow;
    const u16* sA = A + ((size_t)(bm * 256 + w * 32 + srow)) * DM + (schk << 3);
    const u16* sB = W + ((size_t)(bn * 128 + w * 16 + srow)) * DM + (schk << 3);

    int offA[4][2], offB[4][2];
#pragma unroll
    for (int mt = 0; mt < 4; ++mt)
#pragma unroll
        for (int s = 0; s < 2; ++s) {
            const int row = wm + mt * 16 + l4;
            offA[mt][s] = row * 64 + (((s * 4 + q4) ^ (l4 & 7)) << 3);
        }
#pragma unroll
    for (int nt = 0; nt < 4; ++nt)
#pragma unroll
        for (int s = 0; s < 2; ++s) {
            const int row = wn + nt * 16 + l4;
            offB[nt][s] = 16384 + row * 64 + (((s * 4 + q4) ^ (l4 & 7)) << 3);
        }

    auto STAGE = [&](int kt, int b) {
        const u16* a0 = sA + kt * 64;
        const u16* b0 = sB + kt * 64;
        u16* la = lds + b * 24576 + w * 2048;
        u16* lb = lds + b * 24576 + 16384 + w * 1024;
        GLD16(a0,           la);
        GLD16(a0 + 8 * DM,  la + 512);
        GLD16(a0 + 16 * DM, la + 1024);
        GLD16(a0 + 24 * DM, la + 1536);
        GLD16(b0,           lb);
        GLD16(b0 + 8 * DM,  lb + 512);
    };

    f32x4 acc[4][4] = {};

    STAGE(0, 0); STAGE(1, 1); STAGE(2, 2);

#pragma unroll
    for (int kt = 0; kt < 16; ++kt) {
        const int b = kt % 3;
        if (kt < 14)      wait_vm12();
        else if (kt == 14) wait_vm6();
        else               wait_vm0();
        __builtin_amdgcn_s_barrier();
        __builtin_amdgcn_sched_barrier(0);
        const u16* base = lds + b * 24576;
        bf16x8 af[4][2], bfr[4][2];
#pragma unroll
        for (int mt = 0; mt < 4; ++mt)
#pragma unroll
            for (int s = 0; s < 2; ++s) af[mt][s] = ld8(base + offA[mt][s]);
#pragma unroll
        for (int nt = 0; nt < 2; ++nt)
#pragma unroll
            for (int s = 0; s < 2; ++s) bfr[nt][s] = ld8(base + offB[nt][s]);
        __builtin_amdgcn_s_setprio(1);
#pragma unroll
        for (int mt = 0; mt < 4; ++mt)
#pragma unroll
            for (int nt = 0; nt < 2; ++nt)
#pragma unroll
                for (int s = 0; s < 2; ++s)
                    acc[mt][nt] = __builtin_amdgcn_mfma_f32_16x16x32_bf16(af[mt][s], bfr[nt][s], acc[mt][nt], 0, 0, 0);
        __builtin_amdgcn_s_setprio(0);
#pragma unroll
        for (int nt = 2; nt < 4; ++nt)
#pragma unroll
            for (int s = 0; s < 2; ++s) bfr[nt][s] = ld8(base + offB[nt][s]);
        __builtin_amdgcn_s_setprio(1);
#pragma unroll
        for (int mt = 0; mt < 4; ++mt)
#pragma unroll
            for (int nt = 2; nt < 4; ++nt)
#pragma unroll
                for (int s = 0; s < 2; ++s)
                    acc[mt][nt] = __builtin_amdgcn_mfma_f32_16x16x32_bf16(af[mt][s], bfr[nt][s], acc[mt][nt], 0, 0, 0);
        __builtin_amdgcn_s_setprio(0);
        __builtin_amdgcn_s_barrier();
        __builtin_amdgcn_sched_barrier(0);
        if (kt < 13) STAGE(kt + 3, b);
    }

#pragma unroll
    for (int nt = 0; nt < 4; ++nt) {
        const int cc = bn * 128 + wn + nt * 16 + l4;
        const float bs = bf2f(bias[cc]);
#pragma unroll
        for (int mt = 0; mt < 4; ++mt) {
            const int row0 = bm * 256 + wm + mt * 16 + q4 * 4;
            if (fp32m) {
#pragma unroll
                for (int r = 0; r < 4; ++r)
                    ((float*)o0)[(size_t)(row0 + r) * DM + cc] = acc[mt][nt][r] + bs;
            } else {
#pragma unroll
                for (int r = 0; r < 4; ++r)
                    o0[(size_t)(row0 + r) * DM + cc] = f2bf(acc[mt][nt][r] + bs);
            }
        }
    }
}

// Out projection: grid (32, 8) = 256 blocks = exactly 1 wave of 256 CUs.
__global__ __launch_bounds__(512, 2) void gemm_out_k(const u16* __restrict__ Z, const u16* __restrict__ Wc,
                                                     const u16* __restrict__ Vc,
                                                     u16* __restrict__ out, const int* __restrict__ flagp) {
    __shared__ alignas(16) u16 lds[LDS_U16];
    const int fp32m = *flagp;
    gemm256x128_out(lds, Z, Wc + 3 * 1048576, Vc + 3 * 1024, out, fp32m);
}

// ---------------- Flash attention (causal, fixed-max softmax, LDS-staged K/V) ----
__global__ __launch_bounds__(256, 4) void flash_k(const u16* __restrict__ Q,
                                                  const u16* __restrict__ K,
                                                  const u16* __restrict__ Vt,
                                                  u16* __restrict__ Z) {
    const int bh = blockIdx.x;
    const int qb = 15 - (int)blockIdx.y;       // heavy q-blocks dispatch first
    const int n = bh >> 4, h = bh & 15;
    const int tid = threadIdx.x, wave = tid >> 6, lane = tid & 63;
    const int l4 = lane & 15, q4 = lane >> 4;

    __shared__ alignas(16) u16 Ks[2][64 * 32];   // [k-half][kv][32 dm]
    __shared__ alignas(16) u16 Vs[2][64 * 32];   // [kv-half][d][32 kv]
    __shared__ alignas(16) u16 Pl[4][2][16 * 72];

    const int Q0w = qb * 128 + wave * 32;
    bf16x8 qf[2][2];
#pragma unroll
    for (int qt = 0; qt < 2; ++qt) {
        const u16* Qr = Q + ((size_t)(n * SEQ + Q0w + qt * 16 + l4)) * DM + h * 64 + q4 * 8;
        qf[qt][0] = ld8(Qr);
        qf[qt][1] = ld8(Qr + 32);
    }

    const int srow = lane >> 2, scol = (lane & 3) * 8;
    const u16* Kg = K + ((size_t)(n * SEQ + wave * 16 + srow)) * DM + h * 64 + scol;
    const u16* Vg = Vt + ((size_t)(n * 1024 + h * 64 + wave * 16 + srow)) * SEQ + scol;
    u16* KsD0 = &Ks[0][wave * 512];
    u16* KsD1 = &Ks[1][wave * 512];
    u16* VsD0 = &Vs[0][wave * 512];
    u16* VsD1 = &Vs[1][wave * 512];

    f32x4 o[2][4] = {};
    float l_acc[2] = {0.f, 0.f};
    const int nch = 2 * qb + 2;

    for (int c = 0; c < nch; ++c) {
        const int kv0 = c * 64;
        const size_t krow = (size_t)kv0 * DM;
        GLD16(Kg + krow, KsD0);
        GLD16(Kg + krow + 32, KsD1);
        GLD16(Vg + kv0, VsD0);
        GLD16(Vg + kv0 + 32, VsD1);
        __syncthreads();

        bf16x8 a[4][2];
#pragma unroll
        for (int mt = 0; mt < 4; ++mt) {
            a[mt][0] = ld8(&Ks[0][(mt * 16 + l4) * 32 + q4 * 8]);
            a[mt][1] = ld8(&Ks[1][(mt * 16 + l4) * 32 + q4 * 8]);
        }
#pragma unroll
        for (int qt = 0; qt < 2; ++qt) {
            f32x4 st[4];
#pragma unroll
            for (int mt = 0; mt < 4; ++mt) {
                f32x4 zz = {0.f, 0.f, 0.f, 0.f};
                st[mt] = __builtin_amdgcn_mfma_f32_16x16x32_bf16(a[mt][0], qf[qt][0], zz, 0, 0, 0);
                st[mt] = __builtin_amdgcn_mfma_f32_16x16x32_bf16(a[mt][1], qf[qt][1], st[mt], 0, 0, 0);
            }
            const int qg = Q0w + qt * 16 + l4;
            u16* P = Pl[wave][qt];
            float la = l_acc[qt];
#pragma unroll
            for (int mt = 0; mt < 4; ++mt) {
                __bf16 pk[4];
#pragma unroll
                for (int r = 0; r < 4; ++r) {
                    const int kv = kv0 + mt * 16 + q4 * 4 + r;
                    float p = __builtin_amdgcn_exp2f(st[mt][r]);
                    p = (kv > qg) ? 0.f : p;
                    la += p;
                    pk[r] = (__bf16)p;
                }
                *(u16x4*)(P + l4 * 72 + mt * 16 + q4 * 4) = *(u16x4*)pk;
            }
            l_acc[qt] = la;
        }
#pragma unroll
        for (int ks = 0; ks < 2; ++ks) {
            bf16x8 pf0 = ld8(&Pl[wave][0][l4 * 72 + ks * 32 + q4 * 8]);
            bf16x8 pf1 = ld8(&Pl[wave][1][l4 * 72 + ks * 32 + q4 * 8]);
#pragma unroll
            for (int nt = 0; nt < 4; ++nt) {
                bf16x8 vf = ld8(&Vs[ks][(nt * 16 + l4) * 32 + q4 * 8]);
                o[0][nt] = __builtin_amdgcn_mfma_f32_16x16x32_bf16(pf0, vf, o[0][nt], 0, 0, 0);
                o[1][nt] = __builtin_amdgcn_mfma_f32_16x16x32_bf16(pf1, vf, o[1][nt], 0, 0, 0);
            }
        }
        __syncthreads();
    }

#pragma unroll
    for (int qt = 0; qt < 2; ++qt) {
        float l = l_acc[qt];
        l += __shfl_xor(l, 16);
        l += __shfl_xor(l, 32);
        float lr[4];
#pragma unroll
        for (int r = 0; r < 4; ++r) lr[r] = 1.f / __shfl(l, q4 * 4 + r);
#pragma unroll
        for (int nt = 0; nt < 4; ++nt) {
            const int col = h * 64 + nt * 16 + l4;
#pragma unroll
            for (int r = 0; r < 4; ++r) {
                const int row = n * SEQ + Q0w + qt * 16 + q4 * 4 + r;
                Z[(size_t)row * DM + col] = f2bf(o[qt][nt][r] * lr[r]);
            }
        }
    }
}

extern "C" void kernel_launch(void* const* d_in, const int* in_sizes, int n_in,
                              void* d_out, int out_size, void* d_ws, size_t ws_size,
                              hipStream_t stream) {
    const void* x  = d_in[0];
    const void* Wq = d_in[1];
    const void* bq = d_in[2];
    const void* Wk = d_in[3];
    const void* bk = d_in[4];
    const void* Wv = d_in[5];
    const void* bv = d_in[6];
    const void* Wo = d_in[7];
    const void* bo = d_in[8];
    const void* g  = d_in[9];
    const void* b  = d_in[10];
    u16* ws = (u16*)d_ws;

    u16* xn  = ws;
    u16* Qb  = ws + (size_t)TOKS;
    u16* Kb  = ws + (size_t)2 * TOKS;
    u16* Vtb = ws + (size_t)3 * TOKS;
    u16* Zb  = ws;  // xn dead after qkv gemm
    u16* Wc  = ws + (size_t)4 * TOKS;
    u16* Vc  = Wc + 4 * 1048576;
    int* flagp = (int*)(Vc + 8 * 1024);

    detect_k<<<dim3(1), 64, 0, stream>>>((const u32*)x, flagp);
    convert_k<<<dim3(1024, 5), 256, 0, stream>>>(Wq, Wk, Wv, Wo, bq, bk, bv, bo, g, b, Wc, Vc, flagp);
    ln_k<<<dim3(4 * SEQ), 256, 0, stream>>>(x, Vc + 4 * 1024, Vc + 5 * 1024, xn, flagp);
    gemm_qkv_k<<<dim3(32, 12), 512, 0, stream>>>(xn, Wc, Vc, Qb, Kb, Vtb);
    flash_k<<<dim3(64, 16), 256, 0, stream>>>(Qb, Kb, Vtb, Zb);
    gemm_out_k<<<dim3(32, 8), 512, 0, stream>>>(Zb, Wc, Vc, (u16*)d_out, flagp);
}

// Round 3
// 256.149 us; speedup vs baseline: 1.0111x; 1.0111x over previous
//
#include <hip/hip_runtime.h>

typedef unsigned short u16;
typedef unsigned int   u32;
typedef __bf16 bf16x8 __attribute__((ext_vector_type(8)));
typedef float  f32x4  __attribute__((ext_vector_type(4)));
typedef unsigned short u16x8 __attribute__((ext_vector_type(8)));
typedef unsigned short u16x4 __attribute__((ext_vector_type(4)));

#define SEQ 2048
#define DM  1024
#define TOKS 8388608  // 4*2048*1024 elements
#define SCLQ 0.18033688f  // log2(e)/8, folded into Q projection

__device__ __forceinline__ float bf2f(u16 u) {
    u32 i = ((u32)u) << 16;
    float f; __builtin_memcpy(&f, &i, 4); return f;
}
__device__ __forceinline__ u16 f2bf(float f) {
    u32 i; __builtin_memcpy(&i, &f, 4);
    return (u16)((i + 0x7FFFu + ((i >> 16) & 1u)) >> 16);  // RNE
}
__device__ __forceinline__ bf16x8 ld8(const u16* p) {
    return __builtin_bit_cast(bf16x8, *(const u16x8*)p);
}
#define GLD16(src, dst) __builtin_amdgcn_global_load_lds( \
    (const __attribute__((address_space(1))) void*)(src), \
    (__attribute__((address_space(3))) void*)(dst), 16, 0, 0)

// compiler+machine fence around a raw barrier (no vmcnt drain)
#define SBAR() do { asm volatile("" ::: "memory"); __builtin_amdgcn_sched_barrier(0); \
    __builtin_amdgcn_s_barrier(); __builtin_amdgcn_sched_barrier(0); asm volatile("" ::: "memory"); } while (0)
#define WVM(n) asm volatile("s_waitcnt vmcnt(" #n ")" ::: "memory")

// ---------------- dtype detection: bf16 vs fp32 inputs ----------------
__global__ __launch_bounds__(64) void detect_k(const u32* __restrict__ x, int* __restrict__ flag) {
    const int lane = threadIdx.x;
    u32 w = x[lane];
    int e0 = (int)((w >> 7) & 0xFFu);
    int cnt = (e0 >= 100 && e0 <= 140) ? 1 : 0;
#pragma unroll
    for (int off = 32; off; off >>= 1) cnt += __shfl_xor(cnt, off);
    if (lane == 0) *flag = (cnt < 32) ? 1 : 0;   // 1 = fp32 inputs
}

// ---------------- convert weights/vectors to bf16 in ws ----------------
__global__ __launch_bounds__(256) void convert_k(const void* s0, const void* s1, const void* s2, const void* s3,
                                                 const void* v0, const void* v1, const void* v2, const void* v3,
                                                 const void* v4, const void* v5,
                                                 u16* __restrict__ dstW, u16* __restrict__ dstV,
                                                 const int* __restrict__ flagp) {
    const int y = blockIdx.y, tid = threadIdx.x;
    const int fp32m = *flagp;
    const void* src; u16* dst; size_t off;
    if (y < 4) {
        src = (y == 0) ? s0 : (y == 1) ? s1 : (y == 2) ? s2 : s3;
        dst = dstW + (size_t)y * 1048576;
        off = (size_t)blockIdx.x * 1024 + tid * 4;
    } else {
        const int i = blockIdx.x;
        if (i >= 6) return;
        src = (i == 0) ? v0 : (i == 1) ? v1 : (i == 2) ? v2 : (i == 3) ? v3 : (i == 4) ? v4 : v5;
        dst = dstV + (size_t)i * 1024;
        off = (size_t)tid * 4;
    }
    u16x4 o;
    if (fp32m) {
        const float* f = (const float*)src + off;
#pragma unroll
        for (int j = 0; j < 4; ++j) o[j] = f2bf(f[j]);
    } else {
        o = *(const u16x4*)((const u16*)src + off);
    }
    *(u16x4*)(dst + off) = o;
}

// ---------------- LayerNorm: one block per token row ----------------
__global__ __launch_bounds__(256) void ln_k(const void* __restrict__ xv,
                                            const u16* __restrict__ g,
                                            const u16* __restrict__ b,
                                            u16* __restrict__ xn,
                                            const int* __restrict__ flagp) {
    const int row = blockIdx.x, tid = threadIdx.x;
    const int fp32m = *flagp;
    float f[4], s1 = 0.f, s2 = 0.f;
    if (fp32m) {
        f32x4 v = *(const f32x4*)((const float*)xv + (size_t)row * DM + tid * 4);
#pragma unroll
        for (int j = 0; j < 4; ++j) f[j] = v[j];
    } else {
        u16x4 v = *(const u16x4*)((const u16*)xv + (size_t)row * DM + tid * 4);
#pragma unroll
        for (int j = 0; j < 4; ++j) f[j] = bf2f(v[j]);
    }
#pragma unroll
    for (int j = 0; j < 4; ++j) { s1 += f[j]; s2 += f[j] * f[j]; }
#pragma unroll
    for (int off = 32; off; off >>= 1) { s1 += __shfl_xor(s1, off); s2 += __shfl_xor(s2, off); }
    __shared__ float red[8];
    const int wave = tid >> 6, lane = tid & 63;
    if (lane == 0) { red[wave] = s1; red[4 + wave] = s2; }
    __syncthreads();
    s1 = red[0] + red[1] + red[2] + red[3];
    s2 = red[4] + red[5] + red[6] + red[7];
    const float mu = s1 * (1.f / DM);
    const float var = s2 * (1.f / DM) - mu * mu;
    const float rs = rsqrtf(var + 1e-5f);
    u16x4 gv = *(const u16x4*)(g + tid * 4);
    u16x4 bv = *(const u16x4*)(b + tid * 4);
    u16x4 o;
#pragma unroll
    for (int j = 0; j < 4; ++j) o[j] = f2bf((f[j] - mu) * rs * bf2f(gv[j]) + bf2f(bv[j]));
    *(u16x4*)(xn + (size_t)row * DM + tid * 4) = o;
}

// ============ QKV GEMM: 256x256 tile, 4-phase/K-tile, register-lean ============
// 8 waves (2M x 4N), per-wave 128x64 output. LDS: 2 buffers x (A[256][64] +
// B[256][64]) bf16 = 128 KiB, chunk-XOR swizzle (chunk ^= row&7) on both sides.
// Half-tiles (16 KB = 2 GLD16/wave), staged in CONSUMPTION order:
//   P1 stages A-lo (rows {0-63,128-191})     -- needed at next tile's P1
//   P2 stages B-lo (col-stripes s*64+0..31)  -- needed at next tile's P1
//   P3 stages B-hi (col-stripes s*64+32..63) -- needed at next tile's P2
//   P4 stages A-hi (rows {64-127,192-255})   -- needed at next tile's P3
// C-quadrant ring: P1=(Mlo,Nlo) reads A-lo+B-lo | P2=(Mlo,Nhi) reads B-hi,
// keeps A-lo | P3=(Mhi,Nhi) reads A-hi, keeps B-hi | P4=(Mhi,Nlo) re-reads
// B-lo, keeps A-hi.  Max live frags = 8+4 b128 = 48 VGPR (R2's 80 spilled:
// 128 acc AGPR + 80 > 256-reg cap for 8-wave blocks -> 97 MB scratch writes).
// vmcnt(4) at P1-P3 guarantees exactly the half-tile each phase needs
// (steady-state queue: [A-lo,B-lo,B-hi,A-hi] oldest-first; tail 4/2/0).
// P4 needs no barrier: its read target has been globally visible since P1's
// barrier; buffer-overwrite safety is provided by next tile's P1 barrier.
// K accumulation order identical to the original 32-step loop (bit-exact).
__global__ __launch_bounds__(512, 2) void gemm_qkv_k(const u16* __restrict__ xn, const u16* __restrict__ Wc,
                                                     const u16* __restrict__ Vc,
                                                     u16* __restrict__ Q, u16* __restrict__ K, u16* __restrict__ Vt) {
    __shared__ alignas(16) u16 lds[65536];   // 131072 B
    const int tid = threadIdx.x;
    const int w = tid >> 6, lane = tid & 63;
    const int l4 = lane & 15, q4 = lane >> 4;
    const int bm = blockIdx.x, bn = blockIdx.y;
    const int wm0 = (w >> 2) * 128, wn = (w & 3) * 64;

    // staging source (pre-swizzled 16B chunk; rows in groups of 8 so row&7==srow)
    const int srow = lane >> 3, schk = (lane & 7) ^ srow;
    const u16* aS = xn + ((size_t)(bm * 256) + srow) * DM + schk * 8;
    const u16* bS = Wc + ((size_t)(bn * 256) + srow) * DM + schk * 8;
    const int bg0 = (w >> 1) * 64 + (w & 1) * 16;   // B-lo group base (n-space)

    auto STG = [&](int h, int kt, int bufb) {
        const size_t kk = (size_t)kt * 64;
        u16* ld0 = lds + bufb * 32768;
        if (h == 0) {
            GLD16(aS + (size_t)(8 * w) * DM + kk,        ld0 + (8 * w) * 64);
            GLD16(aS + (size_t)(128 + 8 * w) * DM + kk,  ld0 + (128 + 8 * w) * 64);
        } else if (h == 2) {
            GLD16(aS + (size_t)(64 + 8 * w) * DM + kk,   ld0 + (64 + 8 * w) * 64);
            GLD16(aS + (size_t)(192 + 8 * w) * DM + kk,  ld0 + (192 + 8 * w) * 64);
        } else {
            const int b0 = bg0 + ((h == 3) ? 32 : 0);
            GLD16(bS + (size_t)b0 * DM + kk,             ld0 + 16384 + b0 * 64);
            GLD16(bS + (size_t)(b0 + 8) * DM + kk,       ld0 + 16384 + (b0 + 8) * 64);
        }
    };

    // swizzled read offsets (u16 units): row*64 + ((chunk ^ (row&7))<<3)
    const int swz0 = (q4 ^ (l4 & 7)) << 3;        // k-slice 0: logical chunk q4
    const int swz1 = ((4 + q4) ^ (l4 & 7)) << 3;  // k-slice 1: logical chunk 4+q4
    const int arow = (wm0 + l4) * 64;
    const int brow = 16384 + (wn + l4) * 64;

    f32x4 acc[8][4] = {};
    bf16x8 afA[4][2], bfr[2][2];   // ONE A-set + ONE B-set live at a time

    // prologue: stage kt0's half-tiles in consumption order
    STG(0, 0, 0); STG(1, 0, 0); STG(3, 0, 0); STG(2, 0, 0);   // 8 loads in flight

#pragma unroll
    for (int kt = 0; kt < 16; ++kt) {
        const int buf = kt & 1, nxt = buf ^ 1;
        const u16* bp = lds + buf * 32768;
        const bool pf = (kt < 15);
        // ---- P1: quadrant (Mlo, Nlo); waits A-lo + B-lo ----
        WVM(4); SBAR();
        if (pf) STG(0, kt + 1, nxt);
#pragma unroll
        for (int mt = 0; mt < 4; ++mt) {
            afA[mt][0] = ld8(bp + arow + mt * 1024 + swz0);
            afA[mt][1] = ld8(bp + arow + mt * 1024 + swz1);
        }
#pragma unroll
        for (int nt = 0; nt < 2; ++nt) {
            bfr[nt][0] = ld8(bp + brow + nt * 1024 + swz0);
            bfr[nt][1] = ld8(bp + brow + nt * 1024 + swz1);
        }
        __builtin_amdgcn_s_setprio(1);
#pragma unroll
        for (int mt = 0; mt < 4; ++mt)
#pragma unroll
            for (int nt = 0; nt < 2; ++nt) {
                acc[mt][nt] = __builtin_amdgcn_mfma_f32_16x16x32_bf16(afA[mt][0], bfr[nt][0], acc[mt][nt], 0, 0, 0);
                acc[mt][nt] = __builtin_amdgcn_mfma_f32_16x16x32_bf16(afA[mt][1], bfr[nt][1], acc[mt][nt], 0, 0, 0);
            }
        __builtin_amdgcn_s_setprio(0);
        // ---- P2: quadrant (Mlo, Nhi); waits B-hi; A-lo kept in regs ----
        if (pf) { WVM(4); } else { WVM(2); }
        SBAR();
        if (pf) STG(1, kt + 1, nxt);
#pragma unroll
        for (int nt = 0; nt < 2; ++nt) {
            bfr[nt][0] = ld8(bp + brow + (nt + 2) * 1024 + swz0);
            bfr[nt][1] = ld8(bp + brow + (nt + 2) * 1024 + swz1);
        }
        __builtin_amdgcn_s_setprio(1);
#pragma unroll
        for (int mt = 0; mt < 4; ++mt)
#pragma unroll
            for (int nt = 0; nt < 2; ++nt) {
                acc[mt][nt + 2] = __builtin_amdgcn_mfma_f32_16x16x32_bf16(afA[mt][0], bfr[nt][0], acc[mt][nt + 2], 0, 0, 0);
                acc[mt][nt + 2] = __builtin_amdgcn_mfma_f32_16x16x32_bf16(afA[mt][1], bfr[nt][1], acc[mt][nt + 2], 0, 0, 0);
            }
        __builtin_amdgcn_s_setprio(0);
        // ---- P3: quadrant (Mhi, Nhi); waits A-hi; B-hi kept in regs ----
        if (pf) { WVM(4); } else { WVM(0); }
        SBAR();
        if (pf) STG(3, kt + 1, nxt);
#pragma unroll
        for (int mt = 0; mt < 4; ++mt) {
            afA[mt][0] = ld8(bp + arow + (mt + 4) * 1024 + swz0);
            afA[mt][1] = ld8(bp + arow + (mt + 4) * 1024 + swz1);
        }
        __builtin_amdgcn_s_setprio(1);
#pragma unroll
        for (int mt = 0; mt < 4; ++mt)
#pragma unroll
            for (int nt = 0; nt < 2; ++nt) {
                acc[mt + 4][nt + 2] = __builtin_amdgcn_mfma_f32_16x16x32_bf16(afA[mt][0], bfr[nt][0], acc[mt + 4][nt + 2], 0, 0, 0);
                acc[mt + 4][nt + 2] = __builtin_amdgcn_mfma_f32_16x16x32_bf16(afA[mt][1], bfr[nt][1], acc[mt + 4][nt + 2], 0, 0, 0);
            }
        __builtin_amdgcn_s_setprio(0);
        // ---- P4: quadrant (Mhi, Nlo); re-reads B-lo (visible since P1) ----
        if (pf) STG(2, kt + 1, nxt);
#pragma unroll
        for (int nt = 0; nt < 2; ++nt) {
            bfr[nt][0] = ld8(bp + brow + nt * 1024 + swz0);
            bfr[nt][1] = ld8(bp + brow + nt * 1024 + swz1);
        }
        __builtin_amdgcn_s_setprio(1);
#pragma unroll
        for (int mt = 0; mt < 4; ++mt)
#pragma unroll
            for (int nt = 0; nt < 2; ++nt) {
                acc[mt + 4][nt] = __builtin_amdgcn_mfma_f32_16x16x32_bf16(afA[mt][0], bfr[nt][0], acc[mt + 4][nt], 0, 0, 0);
                acc[mt + 4][nt] = __builtin_amdgcn_mfma_f32_16x16x32_bf16(afA[mt][1], bfr[nt][1], acc[mt + 4][nt], 0, 0, 0);
            }
        __builtin_amdgcn_s_setprio(0);
    }

    // ---- epilogue: bn covers 256 cols of the 3072-wide fused QKV output ----
    const int whichB = bn >> 2;                    // 0:Q 1:K 2:V (block-uniform)
    const int cb = (bn & 3) * 256 + wn;
    u16* outp = (whichB == 0) ? Q : (whichB == 1) ? K : Vt;
    const float scl = (whichB == 0) ? SCLQ : 1.0f;
#pragma unroll
    for (int nt = 0; nt < 4; ++nt) {
        const int cc = cb + nt * 16 + l4;
        const float bs = bf2f(Vc[whichB * 1024 + cc]);
#pragma unroll
        for (int mt = 0; mt < 8; ++mt) {
            const int row0 = bm * 256 + wm0 + mt * 16 + q4 * 4;
            if (whichB < 2) {
#pragma unroll
                for (int r = 0; r < 4; ++r)
                    outp[(size_t)(row0 + r) * DM + cc] = f2bf((acc[mt][nt][r] + bs) * scl);
            } else {
                const int nb = row0 >> 11, s0 = row0 & 2047;
                u16x4 pk;
#pragma unroll
                for (int r = 0; r < 4; ++r) pk[r] = f2bf(acc[mt][nt][r] + bs);
                *(u16x4*)(outp + ((size_t)(nb * 1024 + cc)) * SEQ + s0) = pk;
            }
        }
    }
}

// ========== out-projection: verified Round-1 256x128 3-buffer core ==========
#define LDS_U16 73728   // 3 * 24576 u16 = 147456 B

__device__ __forceinline__ void wait_vm12() { asm volatile("s_waitcnt vmcnt(12)" ::: "memory"); }
__device__ __forceinline__ void wait_vm6()  { asm volatile("s_waitcnt vmcnt(6)"  ::: "memory"); }
__device__ __forceinline__ void wait_vm0()  { asm volatile("s_waitcnt vmcnt(0)"  ::: "memory"); }

__device__ __forceinline__ void gemm256x128_out(u16* lds,
                                                const u16* __restrict__ A,
                                                const u16* __restrict__ W,
                                                const u16* __restrict__ bias,
                                                u16* __restrict__ o0,
                                                int fp32m) {
    const int tid = threadIdx.x;
    const int w = tid >> 6, lane = tid & 63;
    const int l4 = lane & 15, q4 = lane >> 4;
    const int bm = blockIdx.x, bn = blockIdx.y;
    const int wm = (w >> 1) * 64, wn = (w & 1) * 64;

    const int srow = lane >> 3;
    const int schk = (lane & 7) ^ srow;
    const u16* sA = A + ((size_t)(bm * 256 + w * 32 + srow)) * DM + (schk << 3);
    const u16* sB = W + ((size_t)(bn * 128 + w * 16 + srow)) * DM + (schk << 3);

    int offA[4][2], offB[4][2];
#pragma unroll
    for (int mt = 0; mt < 4; ++mt)
#pragma unroll
        for (int s = 0; s < 2; ++s) {
            const int row = wm + mt * 16 + l4;
            offA[mt][s] = row * 64 + (((s * 4 + q4) ^ (l4 & 7)) << 3);
        }
#pragma unroll
    for (int nt = 0; nt < 4; ++nt)
#pragma unroll
        for (int s = 0; s < 2; ++s) {
            const int row = wn + nt * 16 + l4;
            offB[nt][s] = 16384 + row * 64 + (((s * 4 + q4) ^ (l4 & 7)) << 3);
        }

    auto STAGE = [&](int kt, int b) {
        const u16* a0 = sA + kt * 64;
        const u16* b0 = sB + kt * 64;
        u16* la = lds + b * 24576 + w * 2048;
        u16* lb = lds + b * 24576 + 16384 + w * 1024;
        GLD16(a0,           la);
        GLD16(a0 + 8 * DM,  la + 512);
        GLD16(a0 + 16 * DM, la + 1024);
        GLD16(a0 + 24 * DM, la + 1536);
        GLD16(b0,           lb);
        GLD16(b0 + 8 * DM,  lb + 512);
    };

    f32x4 acc[4][4] = {};

    STAGE(0, 0); STAGE(1, 1); STAGE(2, 2);

#pragma unroll
    for (int kt = 0; kt < 16; ++kt) {
        const int b = kt % 3;
        if (kt < 14)      wait_vm12();
        else if (kt == 14) wait_vm6();
        else               wait_vm0();
        __builtin_amdgcn_s_barrier();
        __builtin_amdgcn_sched_barrier(0);
        const u16* base = lds + b * 24576;
        bf16x8 af[4][2], bfr[4][2];
#pragma unroll
        for (int mt = 0; mt < 4; ++mt)
#pragma unroll
            for (int s = 0; s < 2; ++s) af[mt][s] = ld8(base + offA[mt][s]);
#pragma unroll
        for (int nt = 0; nt < 2; ++nt)
#pragma unroll
            for (int s = 0; s < 2; ++s) bfr[nt][s] = ld8(base + offB[nt][s]);
        __builtin_amdgcn_s_setprio(1);
#pragma unroll
        for (int mt = 0; mt < 4; ++mt)
#pragma unroll
            for (int nt = 0; nt < 2; ++nt)
#pragma unroll
                for (int s = 0; s < 2; ++s)
                    acc[mt][nt] = __builtin_amdgcn_mfma_f32_16x16x32_bf16(af[mt][s], bfr[nt][s], acc[mt][nt], 0, 0, 0);
        __builtin_amdgcn_s_setprio(0);
#pragma unroll
        for (int nt = 2; nt < 4; ++nt)
#pragma unroll
            for (int s = 0; s < 2; ++s) bfr[nt][s] = ld8(base + offB[nt][s]);
        __builtin_amdgcn_s_setprio(1);
#pragma unroll
        for (int mt = 0; mt < 4; ++mt)
#pragma unroll
            for (int nt = 2; nt < 4; ++nt)
#pragma unroll
                for (int s = 0; s < 2; ++s)
                    acc[mt][nt] = __builtin_amdgcn_mfma_f32_16x16x32_bf16(af[mt][s], bfr[nt][s], acc[mt][nt], 0, 0, 0);
        __builtin_amdgcn_s_setprio(0);
        __builtin_amdgcn_s_barrier();
        __builtin_amdgcn_sched_barrier(0);
        if (kt < 13) STAGE(kt + 3, b);
    }

#pragma unroll
    for (int nt = 0; nt < 4; ++nt) {
        const int cc = bn * 128 + wn + nt * 16 + l4;
        const float bs = bf2f(bias[cc]);
#pragma unroll
        for (int mt = 0; mt < 4; ++mt) {
            const int row0 = bm * 256 + wm + mt * 16 + q4 * 4;
            if (fp32m) {
#pragma unroll
                for (int r = 0; r < 4; ++r)
                    ((float*)o0)[(size_t)(row0 + r) * DM + cc] = acc[mt][nt][r] + bs;
            } else {
#pragma unroll
                for (int r = 0; r < 4; ++r)
                    o0[(size_t)(row0 + r) * DM + cc] = f2bf(acc[mt][nt][r] + bs);
            }
        }
    }
}

// Out projection: grid (32, 8) = 256 blocks = exactly 1 wave of 256 CUs.
__global__ __launch_bounds__(512, 2) void gemm_out_k(const u16* __restrict__ Z, const u16* __restrict__ Wc,
                                                     const u16* __restrict__ Vc,
                                                     u16* __restrict__ out, const int* __restrict__ flagp) {
    __shared__ alignas(16) u16 lds[LDS_U16];
    const int fp32m = *flagp;
    gemm256x128_out(lds, Z, Wc + 3 * 1048576, Vc + 3 * 1024, out, fp32m);
}

// ---------------- Flash attention (causal, fixed-max softmax, LDS-staged K/V) ----
__global__ __launch_bounds__(256, 4) void flash_k(const u16* __restrict__ Q,
                                                  const u16* __restrict__ K,
                                                  const u16* __restrict__ Vt,
                                                  u16* __restrict__ Z) {
    const int bh = blockIdx.x;
    const int qb = 15 - (int)blockIdx.y;       // heavy q-blocks dispatch first
    const int n = bh >> 4, h = bh & 15;
    const int tid = threadIdx.x, wave = tid >> 6, lane = tid & 63;
    const int l4 = lane & 15, q4 = lane >> 4;

    __shared__ alignas(16) u16 Ks[2][64 * 32];   // [k-half][kv][32 dm]
    __shared__ alignas(16) u16 Vs[2][64 * 32];   // [kv-half][d][32 kv]
    __shared__ alignas(16) u16 Pl[4][2][16 * 72];

    const int Q0w = qb * 128 + wave * 32;
    bf16x8 qf[2][2];
#pragma unroll
    for (int qt = 0; qt < 2; ++qt) {
        const u16* Qr = Q + ((size_t)(n * SEQ + Q0w + qt * 16 + l4)) * DM + h * 64 + q4 * 8;
        qf[qt][0] = ld8(Qr);
        qf[qt][1] = ld8(Qr + 32);
    }

    const int srow = lane >> 2, scol = (lane & 3) * 8;
    const u16* Kg = K + ((size_t)(n * SEQ + wave * 16 + srow)) * DM + h * 64 + scol;
    const u16* Vg = Vt + ((size_t)(n * 1024 + h * 64 + wave * 16 + srow)) * SEQ + scol;
    u16* KsD0 = &Ks[0][wave * 512];
    u16* KsD1 = &Ks[1][wave * 512];
    u16* VsD0 = &Vs[0][wave * 512];
    u16* VsD1 = &Vs[1][wave * 512];

    f32x4 o[2][4] = {};
    float l_acc[2] = {0.f, 0.f};
    const int nch = 2 * qb + 2;

    for (int c = 0; c < nch; ++c) {
        const int kv0 = c * 64;
        const size_t krow = (size_t)kv0 * DM;
        GLD16(Kg + krow, KsD0);
        GLD16(Kg + krow + 32, KsD1);
        GLD16(Vg + kv0, VsD0);
        GLD16(Vg + kv0 + 32, VsD1);
        __syncthreads();

        bf16x8 a[4][2];
#pragma unroll
        for (int mt = 0; mt < 4; ++mt) {
            a[mt][0] = ld8(&Ks[0][(mt * 16 + l4) * 32 + q4 * 8]);
            a[mt][1] = ld8(&Ks[1][(mt * 16 + l4) * 32 + q4 * 8]);
        }
#pragma unroll
        for (int qt = 0; qt < 2; ++qt) {
            f32x4 st[4];
#pragma unroll
            for (int mt = 0; mt < 4; ++mt) {
                f32x4 zz = {0.f, 0.f, 0.f, 0.f};
                st[mt] = __builtin_amdgcn_mfma_f32_16x16x32_bf16(a[mt][0], qf[qt][0], zz, 0, 0, 0);
                st[mt] = __builtin_amdgcn_mfma_f32_16x16x32_bf16(a[mt][1], qf[qt][1], st[mt], 0, 0, 0);
            }
            const int qg = Q0w + qt * 16 + l4;
            u16* P = Pl[wave][qt];
            float la = l_acc[qt];
#pragma unroll
            for (int mt = 0; mt < 4; ++mt) {
                __bf16 pk[4];
#pragma unroll
                for (int r = 0; r < 4; ++r) {
                    const int kv = kv0 + mt * 16 + q4 * 4 + r;
                    float p = __builtin_amdgcn_exp2f(st[mt][r]);
                    p = (kv > qg) ? 0.f : p;
                    la += p;
                    pk[r] = (__bf16)p;
                }
                *(u16x4*)(P + l4 * 72 + mt * 16 + q4 * 4) = *(u16x4*)pk;
            }
            l_acc[qt] = la;
        }
#pragma unroll
        for (int ks = 0; ks < 2; ++ks) {
            bf16x8 pf0 = ld8(&Pl[wave][0][l4 * 72 + ks * 32 + q4 * 8]);
            bf16x8 pf1 = ld8(&Pl[wave][1][l4 * 72 + ks * 32 + q4 * 8]);
#pragma unroll
            for (int nt = 0; nt < 4; ++nt) {
                bf16x8 vf = ld8(&Vs[ks][(nt * 16 + l4) * 32 + q4 * 8]);
                o[0][nt] = __builtin_amdgcn_mfma_f32_16x16x32_bf16(pf0, vf, o[0][nt], 0, 0, 0);
                o[1][nt] = __builtin_amdgcn_mfma_f32_16x16x32_bf16(pf1, vf, o[1][nt], 0, 0, 0);
            }
        }
        __syncthreads();
    }

#pragma unroll
    for (int qt = 0; qt < 2; ++qt) {
        float l = l_acc[qt];
        l += __shfl_xor(l, 16);
        l += __shfl_xor(l, 32);
        float lr[4];
#pragma unroll
        for (int r = 0; r < 4; ++r) lr[r] = 1.f / __shfl(l, q4 * 4 + r);
#pragma unroll
        for (int nt = 0; nt < 4; ++nt) {
            const int col = h * 64 + nt * 16 + l4;
#pragma unroll
            for (int r = 0; r < 4; ++r) {
                const int row = n * SEQ + Q0w + qt * 16 + q4 * 4 + r;
                Z[(size_t)row * DM + col] = f2bf(o[qt][nt][r] * lr[r]);
            }
        }
    }
}

extern "C" void kernel_launch(void* const* d_in, const int* in_sizes, int n_in,
                              void* d_out, int out_size, void* d_ws, size_t ws_size,
                              hipStream_t stream) {
    const void* x  = d_in[0];
    const void* Wq = d_in[1];
    const void* bq = d_in[2];
    const void* Wk = d_in[3];
    const void* bk = d_in[4];
    const void* Wv = d_in[5];
    const void* bv = d_in[6];
    const void* Wo = d_in[7];
    const void* bo = d_in[8];
    const void* g  = d_in[9];
    const void* b  = d_in[10];
    u16* ws = (u16*)d_ws;

    u16* xn  = ws;
    u16* Qb  = ws + (size_t)TOKS;
    u16* Kb  = ws + (size_t)2 * TOKS;
    u16* Vtb = ws + (size_t)3 * TOKS;
    u16* Zb  = ws;  // xn dead after qkv gemm
    u16* Wc  = ws + (size_t)4 * TOKS;
    u16* Vc  = Wc + 4 * 1048576;
    int* flagp = (int*)(Vc + 8 * 1024);

    detect_k<<<dim3(1), 64, 0, stream>>>((const u32*)x, flagp);
    convert_k<<<dim3(1024, 5), 256, 0, stream>>>(Wq, Wk, Wv, Wo, bq, bk, bv, bo, g, b, Wc, Vc, flagp);
    ln_k<<<dim3(4 * SEQ), 256, 0, stream>>>(x, Vc + 4 * 1024, Vc + 5 * 1024, xn, flagp);
    gemm_qkv_k<<<dim3(32, 12), 512, 0, stream>>>(xn, Wc, Vc, Qb, Kb, Vtb);
    flash_k<<<dim3(64, 16), 256, 0, stream>>>(Qb, Kb, Vtb, Zb);
    gemm_out_k<<<dim3(32, 8), 512, 0, stream>>>(Zb, Wc, Vc, (u16*)d_out, flagp);
}

// Round 4
// 253.130 us; speedup vs baseline: 1.0232x; 1.0119x over previous
//
#include <hip/hip_runtime.h>

typedef unsigned short u16;
typedef unsigned int   u32;
typedef __bf16 bf16x8 __attribute__((ext_vector_type(8)));
typedef float  f32x4  __attribute__((ext_vector_type(4)));
typedef unsigned short u16x8 __attribute__((ext_vector_type(8)));
typedef unsigned short u16x4 __attribute__((ext_vector_type(4)));

#define SEQ 2048
#define DM  1024
#define TOKS 8388608  // 4*2048*1024 elements
#define SCLQ 0.18033688f  // log2(e)/8, folded into Q projection

__device__ __forceinline__ float bf2f(u16 u) {
    u32 i = ((u32)u) << 16;
    float f; __builtin_memcpy(&f, &i, 4); return f;
}
__device__ __forceinline__ u16 f2bf(float f) {
    u32 i; __builtin_memcpy(&i, &f, 4);
    return (u16)((i + 0x7FFFu + ((i >> 16) & 1u)) >> 16);  // RNE
}
__device__ __forceinline__ bf16x8 ld8(const u16* p) {
    return __builtin_bit_cast(bf16x8, *(const u16x8*)p);
}
#define GLD16(src, dst) __builtin_amdgcn_global_load_lds( \
    (const __attribute__((address_space(1))) void*)(src), \
    (__attribute__((address_space(3))) void*)(dst), 16, 0, 0)

// compiler+machine fence around a raw barrier (no vmcnt drain)
#define SBAR() do { asm volatile("" ::: "memory"); __builtin_amdgcn_sched_barrier(0); \
    __builtin_amdgcn_s_barrier(); __builtin_amdgcn_sched_barrier(0); asm volatile("" ::: "memory"); } while (0)
#define WVM(n) asm volatile("s_waitcnt vmcnt(" #n ")" ::: "memory")

// ---------------- dtype detection: bf16 vs fp32 inputs ----------------
__global__ __launch_bounds__(64) void detect_k(const u32* __restrict__ x, int* __restrict__ flag) {
    const int lane = threadIdx.x;
    u32 w = x[lane];
    int e0 = (int)((w >> 7) & 0xFFu);
    int cnt = (e0 >= 100 && e0 <= 140) ? 1 : 0;
#pragma unroll
    for (int off = 32; off; off >>= 1) cnt += __shfl_xor(cnt, off);
    if (lane == 0) *flag = (cnt < 32) ? 1 : 0;   // 1 = fp32 inputs
}

// ---------------- convert weights/vectors to bf16 in ws ----------------
__global__ __launch_bounds__(256) void convert_k(const void* s0, const void* s1, const void* s2, const void* s3,
                                                 const void* v0, const void* v1, const void* v2, const void* v3,
                                                 const void* v4, const void* v5,
                                                 u16* __restrict__ dstW, u16* __restrict__ dstV,
                                                 const int* __restrict__ flagp) {
    const int y = blockIdx.y, tid = threadIdx.x;
    const int fp32m = *flagp;
    const void* src; u16* dst; size_t off;
    if (y < 4) {
        src = (y == 0) ? s0 : (y == 1) ? s1 : (y == 2) ? s2 : s3;
        dst = dstW + (size_t)y * 1048576;
        off = (size_t)blockIdx.x * 1024 + tid * 4;
    } else {
        const int i = blockIdx.x;
        if (i >= 6) return;
        src = (i == 0) ? v0 : (i == 1) ? v1 : (i == 2) ? v2 : (i == 3) ? v3 : (i == 4) ? v4 : v5;
        dst = dstV + (size_t)i * 1024;
        off = (size_t)tid * 4;
    }
    u16x4 o;
    if (fp32m) {
        const float* f = (const float*)src + off;
#pragma unroll
        for (int j = 0; j < 4; ++j) o[j] = f2bf(f[j]);
    } else {
        o = *(const u16x4*)((const u16*)src + off);
    }
    *(u16x4*)(dst + off) = o;
}

// ---------------- LayerNorm: one block per token row ----------------
__global__ __launch_bounds__(256) void ln_k(const void* __restrict__ xv,
                                            const u16* __restrict__ g,
                                            const u16* __restrict__ b,
                                            u16* __restrict__ xn,
                                            const int* __restrict__ flagp) {
    const int row = blockIdx.x, tid = threadIdx.x;
    const int fp32m = *flagp;
    float f[4], s1 = 0.f, s2 = 0.f;
    if (fp32m) {
        f32x4 v = *(const f32x4*)((const float*)xv + (size_t)row * DM + tid * 4);
#pragma unroll
        for (int j = 0; j < 4; ++j) f[j] = v[j];
    } else {
        u16x4 v = *(const u16x4*)((const u16*)xv + (size_t)row * DM + tid * 4);
#pragma unroll
        for (int j = 0; j < 4; ++j) f[j] = bf2f(v[j]);
    }
#pragma unroll
    for (int j = 0; j < 4; ++j) { s1 += f[j]; s2 += f[j] * f[j]; }
#pragma unroll
    for (int off = 32; off; off >>= 1) { s1 += __shfl_xor(s1, off); s2 += __shfl_xor(s2, off); }
    __shared__ float red[8];
    const int wave = tid >> 6, lane = tid & 63;
    if (lane == 0) { red[wave] = s1; red[4 + wave] = s2; }
    __syncthreads();
    s1 = red[0] + red[1] + red[2] + red[3];
    s2 = red[4] + red[5] + red[6] + red[7];
    const float mu = s1 * (1.f / DM);
    const float var = s2 * (1.f / DM) - mu * mu;
    const float rs = rsqrtf(var + 1e-5f);
    u16x4 gv = *(const u16x4*)(g + tid * 4);
    u16x4 bv = *(const u16x4*)(b + tid * 4);
    u16x4 o;
#pragma unroll
    for (int j = 0; j < 4; ++j) o[j] = f2bf((f[j] - mu) * rs * bf2f(gv[j]) + bf2f(bv[j]));
    *(u16x4*)(xn + (size_t)row * DM + tid * 4) = o;
}

// ============ QKV GEMM: 256x256 tile, BK=32, 4-buffer 3-ahead pipeline ============
// 8 waves (2M x 4N), per-wave 128x64 output. LDS = 4 buffers x 32KB
// (A[256][32] + B[256][32] bf16) = 131072 B (proven size). ONE vmcnt(8) +
// ONE barrier per K-step: stage target (kt+3)%4 is the buffer whose reads
// finished last iteration (WAR covered by this iteration's barrier), so no
// trailing barrier is needed. 12 loads/wave in flight (3 K-steps deep, ~96KB/CU)
// restores R1's latency-hiding depth while BN=256 cuts staged bytes 1.5x
// (590 -> 394 MB): the staging-delivery bound drops from ~66us toward ~45us.
// Chunk-XOR swizzle (chunk ^= (row>>1)&3, 4 chunks/row at BK=32) on both sides:
// pre-swizzled global source (linear GLD dest) + swizzled ds_read -> 64 lanes
// spread uniformly over all 8 bank-quads (2-way = free).
// XCD swizzle: 384 wgs, chunk of 48 per XCD = 4 bm x 12 bn -> 2MB A-panel
// resident per XCD L2.  K accumulation = 32 ascending BK=32 steps (bit-exact
// vs the original kernel).  Max live frags 8 (32 VGPR) -> no spill.
__global__ __launch_bounds__(512, 2) void gemm_qkv_k(const u16* __restrict__ xn, const u16* __restrict__ Wc,
                                                     const u16* __restrict__ Vc,
                                                     u16* __restrict__ Q, u16* __restrict__ K, u16* __restrict__ Vt) {
    __shared__ alignas(16) u16 lds[65536];   // 4 x 16384 u16 = 131072 B
    const int tid = threadIdx.x;
    const int w = tid >> 6, lane = tid & 63;
    const int l4 = lane & 15, q4 = lane >> 4;
    // XCD-chunked swizzle (bijective: 384 % 8 == 0)
    const int orig = blockIdx.y * 32 + blockIdx.x;
    const int s = (orig & 7) * 48 + (orig >> 3);
    const int bm = s / 12, bn = s % 12;
    const int wm0 = (w >> 2) * 128, wn = (w & 3) * 64;

    // staging source: lane -> (row = lane>>2, chunk = (lane&3) ^ ((lane>>3)&3))
    const int srowl = lane >> 2;
    const int schk = (lane & 3) ^ ((lane >> 3) & 3);
    const u16* aS = xn + ((size_t)(bm * 256) + srowl) * DM + schk * 8;
    const u16* bS = Wc + ((size_t)(bn * 256) + srowl) * DM + schk * 8;
    const int rb = w * 16;   // per-wave 16-row staging group

    // h: 0=A-lo 1=B-lo 2=B-hi 3=A-hi  (16 rows x 64B per wave per call)
    auto STG = [&](int h, int kt, int bq) {
        const size_t kk = (size_t)kt * 32;
        u16* d = lds + bq * 16384;
        if (h == 0)      GLD16(aS + (size_t)rb * DM + kk,         d + rb * 32);
        else if (h == 3) GLD16(aS + (size_t)(128 + rb) * DM + kk, d + 4096 + rb * 32);
        else if (h == 1) GLD16(bS + (size_t)rb * DM + kk,         d + 8192 + rb * 32);
        else             GLD16(bS + (size_t)(128 + rb) * DM + kk, d + 12288 + rb * 32);
    };

    // swizzled read offset: row*32 + ((q4 ^ ((l4>>1)&3)) << 3)
    const int swz = (q4 ^ ((l4 >> 1) & 3)) << 3;

    f32x4 acc[8][4] = {};
    bf16x8 af[4], bfv[4];

    // prologue: stage kt 0,1,2 (queue order per kt: A-lo,B-lo,B-hi,A-hi) = 12 loads
#pragma unroll
    for (int p = 0; p < 3; ++p) {
        STG(0, p, p); STG(1, p, p); STG(2, p, p); STG(3, p, p);
    }

    for (int kt = 0; kt < 32; ++kt) {
        if (kt <= 29)      { WVM(8); }   // completes all 4 half-tiles of kt
        else if (kt == 30) { WVM(4); }
        else               { WVM(0); }
        SBAR();
        const u16* bp = lds + (kt & 3) * 16384;
        const bool pf = (kt < 29);
        const int nb = (kt + 3) & 3;
        if (pf) { STG(0, kt + 3, nb); STG(1, kt + 3, nb); }
        // half 1: M rows wm0..wm0+63
#pragma unroll
        for (int mt = 0; mt < 4; ++mt) af[mt] = ld8(bp + (wm0 + mt * 16 + l4) * 32 + swz);
#pragma unroll
        for (int nt = 0; nt < 4; ++nt) bfv[nt] = ld8(bp + 8192 + (wn + nt * 16 + l4) * 32 + swz);
        __builtin_amdgcn_s_setprio(1);
#pragma unroll
        for (int mt = 0; mt < 4; ++mt)
#pragma unroll
            for (int nt = 0; nt < 4; ++nt)
                acc[mt][nt] = __builtin_amdgcn_mfma_f32_16x16x32_bf16(af[mt], bfv[nt], acc[mt][nt], 0, 0, 0);
        __builtin_amdgcn_s_setprio(0);
        if (pf) { STG(2, kt + 3, nb); STG(3, kt + 3, nb); }
        // half 2: M rows wm0+64..wm0+127 (B frags kept)
#pragma unroll
        for (int mt = 0; mt < 4; ++mt) af[mt] = ld8(bp + (wm0 + 64 + mt * 16 + l4) * 32 + swz);
        __builtin_amdgcn_s_setprio(1);
#pragma unroll
        for (int mt = 0; mt < 4; ++mt)
#pragma unroll
            for (int nt = 0; nt < 4; ++nt)
                acc[mt + 4][nt] = __builtin_amdgcn_mfma_f32_16x16x32_bf16(af[mt], bfv[nt], acc[mt + 4][nt], 0, 0, 0);
        __builtin_amdgcn_s_setprio(0);
    }

    // ---- epilogue: bn covers 256 cols of the 3072-wide fused QKV output ----
    const int whichB = bn >> 2;                    // 0:Q 1:K 2:V (block-uniform)
    const int cb = (bn & 3) * 256 + wn;
    u16* outp = (whichB == 0) ? Q : (whichB == 1) ? K : Vt;
    const float scl = (whichB == 0) ? SCLQ : 1.0f;
    float bs4[4];
#pragma unroll
    for (int nt = 0; nt < 4; ++nt) bs4[nt] = bf2f(Vc[whichB * 1024 + cb + nt * 16 + l4]);
    if (whichB < 2) {
        // nt INNERMOST: the 4 chunks of each 128B output line issue back-to-back
        // (prompt line completion -> no partial-dirty-line eviction / write amp)
#pragma unroll
        for (int mt = 0; mt < 8; ++mt) {
            const int row0 = bm * 256 + wm0 + mt * 16 + q4 * 4;
#pragma unroll
            for (int r = 0; r < 4; ++r) {
                u16* rowp = outp + (size_t)(row0 + r) * DM + cb;
#pragma unroll
                for (int nt = 0; nt < 4; ++nt)
                    rowp[nt * 16 + l4] = f2bf((acc[mt][nt][r] + bs4[nt]) * scl);
            }
        }
    } else {
#pragma unroll
        for (int nt = 0; nt < 4; ++nt) {
            const int cc = cb + nt * 16 + l4;
#pragma unroll
            for (int mt = 0; mt < 8; ++mt) {
                const int row0 = bm * 256 + wm0 + mt * 16 + q4 * 4;
                const int nbk = row0 >> 11, s0 = row0 & 2047;
                u16x4 pk;
#pragma unroll
                for (int r = 0; r < 4; ++r) pk[r] = f2bf(acc[mt][nt][r] + bs4[nt]);
                *(u16x4*)(outp + ((size_t)(nbk * 1024 + cc)) * SEQ + s0) = pk;
            }
        }
    }
}

// ========== out-projection: verified Round-1 256x128 3-buffer core ==========
#define LDS_U16 73728   // 3 * 24576 u16 = 147456 B

__device__ __forceinline__ void wait_vm12() { asm volatile("s_waitcnt vmcnt(12)" ::: "memory"); }
__device__ __forceinline__ void wait_vm6()  { asm volatile("s_waitcnt vmcnt(6)"  ::: "memory"); }
__device__ __forceinline__ void wait_vm0()  { asm volatile("s_waitcnt vmcnt(0)"  ::: "memory"); }

__device__ __forceinline__ void gemm256x128_out(u16* lds,
                                                const u16* __restrict__ A,
                                                const u16* __restrict__ W,
                                                const u16* __restrict__ bias,
                                                u16* __restrict__ o0,
                                                int fp32m) {
    const int tid = threadIdx.x;
    const int w = tid >> 6, lane = tid & 63;
    const int l4 = lane & 15, q4 = lane >> 4;
    const int bm = blockIdx.x, bn = blockIdx.y;
    const int wm = (w >> 1) * 64, wn = (w & 1) * 64;

    const int srow = lane >> 3;
    const int schk = (lane & 7) ^ srow;
    const u16* sA = A + ((size_t)(bm * 256 + w * 32 + srow)) * DM + (schk << 3);
    const u16* sB = W + ((size_t)(bn * 128 + w * 16 + srow)) * DM + (schk << 3);

    int offA[4][2], offB[4][2];
#pragma unroll
    for (int mt = 0; mt < 4; ++mt)
#pragma unroll
        for (int s = 0; s < 2; ++s) {
            const int row = wm + mt * 16 + l4;
            offA[mt][s] = row * 64 + (((s * 4 + q4) ^ (l4 & 7)) << 3);
        }
#pragma unroll
    for (int nt = 0; nt < 4; ++nt)
#pragma unroll
        for (int s = 0; s < 2; ++s) {
            const int row = wn + nt * 16 + l4;
            offB[nt][s] = 16384 + row * 64 + (((s * 4 + q4) ^ (l4 & 7)) << 3);
        }

    auto STAGE = [&](int kt, int b) {
        const u16* a0 = sA + kt * 64;
        const u16* b0 = sB + kt * 64;
        u16* la = lds + b * 24576 + w * 2048;
        u16* lb = lds + b * 24576 + 16384 + w * 1024;
        GLD16(a0,           la);
        GLD16(a0 + 8 * DM,  la + 512);
        GLD16(a0 + 16 * DM, la + 1024);
        GLD16(a0 + 24 * DM, la + 1536);
        GLD16(b0,           lb);
        GLD16(b0 + 8 * DM,  lb + 512);
    };

    f32x4 acc[4][4] = {};

    STAGE(0, 0); STAGE(1, 1); STAGE(2, 2);

#pragma unroll
    for (int kt = 0; kt < 16; ++kt) {
        const int b = kt % 3;
        if (kt < 14)      wait_vm12();
        else if (kt == 14) wait_vm6();
        else               wait_vm0();
        __builtin_amdgcn_s_barrier();
        __builtin_amdgcn_sched_barrier(0);
        const u16* base = lds + b * 24576;
        bf16x8 af[4][2], bfr[4][2];
#pragma unroll
        for (int mt = 0; mt < 4; ++mt)
#pragma unroll
            for (int s = 0; s < 2; ++s) af[mt][s] = ld8(base + offA[mt][s]);
#pragma unroll
        for (int nt = 0; nt < 2; ++nt)
#pragma unroll
            for (int s = 0; s < 2; ++s) bfr[nt][s] = ld8(base + offB[nt][s]);
        __builtin_amdgcn_s_setprio(1);
#pragma unroll
        for (int mt = 0; mt < 4; ++mt)
#pragma unroll
            for (int nt = 0; nt < 2; ++nt)
#pragma unroll
                for (int s = 0; s < 2; ++s)
                    acc[mt][nt] = __builtin_amdgcn_mfma_f32_16x16x32_bf16(af[mt][s], bfr[nt][s], acc[mt][nt], 0, 0, 0);
        __builtin_amdgcn_s_setprio(0);
#pragma unroll
        for (int nt = 2; nt < 4; ++nt)
#pragma unroll
            for (int s = 0; s < 2; ++s) bfr[nt][s] = ld8(base + offB[nt][s]);
        __builtin_amdgcn_s_setprio(1);
#pragma unroll
        for (int mt = 0; mt < 4; ++mt)
#pragma unroll
            for (int nt = 2; nt < 4; ++nt)
#pragma unroll
                for (int s = 0; s < 2; ++s)
                    acc[mt][nt] = __builtin_amdgcn_mfma_f32_16x16x32_bf16(af[mt][s], bfr[nt][s], acc[mt][nt], 0, 0, 0);
        __builtin_amdgcn_s_setprio(0);
        __builtin_amdgcn_s_barrier();
        __builtin_amdgcn_sched_barrier(0);
        if (kt < 13) STAGE(kt + 3, b);
    }

#pragma unroll
    for (int nt = 0; nt < 4; ++nt) {
        const int cc = bn * 128 + wn + nt * 16 + l4;
        const float bs = bf2f(bias[cc]);
#pragma unroll
        for (int mt = 0; mt < 4; ++mt) {
            const int row0 = bm * 256 + wm + mt * 16 + q4 * 4;
            if (fp32m) {
#pragma unroll
                for (int r = 0; r < 4; ++r)
                    ((float*)o0)[(size_t)(row0 + r) * DM + cc] = acc[mt][nt][r] + bs;
            } else {
#pragma unroll
                for (int r = 0; r < 4; ++r)
                    o0[(size_t)(row0 + r) * DM + cc] = f2bf(acc[mt][nt][r] + bs);
            }
        }
    }
}

// Out projection: grid (32, 8) = 256 blocks = exactly 1 wave of 256 CUs.
__global__ __launch_bounds__(512, 2) void gemm_out_k(const u16* __restrict__ Z, const u16* __restrict__ Wc,
                                                     const u16* __restrict__ Vc,
                                                     u16* __restrict__ out, const int* __restrict__ flagp) {
    __shared__ alignas(16) u16 lds[LDS_U16];
    const int fp32m = *flagp;
    gemm256x128_out(lds, Z, Wc + 3 * 1048576, Vc + 3 * 1024, out, fp32m);
}

// ---------------- Flash attention (causal, fixed-max softmax, LDS-staged K/V) ----
__global__ __launch_bounds__(256, 4) void flash_k(const u16* __restrict__ Q,
                                                  const u16* __restrict__ K,
                                                  const u16* __restrict__ Vt,
                                                  u16* __restrict__ Z) {
    const int bh = blockIdx.x;
    const int qb = 15 - (int)blockIdx.y;       // heavy q-blocks dispatch first
    const int n = bh >> 4, h = bh & 15;
    const int tid = threadIdx.x, wave = tid >> 6, lane = tid & 63;
    const int l4 = lane & 15, q4 = lane >> 4;

    __shared__ alignas(16) u16 Ks[2][64 * 32];   // [k-half][kv][32 dm]
    __shared__ alignas(16) u16 Vs[2][64 * 32];   // [kv-half][d][32 kv]
    __shared__ alignas(16) u16 Pl[4][2][16 * 72];

    const int Q0w = qb * 128 + wave * 32;
    bf16x8 qf[2][2];
#pragma unroll
    for (int qt = 0; qt < 2; ++qt) {
        const u16* Qr = Q + ((size_t)(n * SEQ + Q0w + qt * 16 + l4)) * DM + h * 64 + q4 * 8;
        qf[qt][0] = ld8(Qr);
        qf[qt][1] = ld8(Qr + 32);
    }

    const int srow = lane >> 2, scol = (lane & 3) * 8;
    const u16* Kg = K + ((size_t)(n * SEQ + wave * 16 + srow)) * DM + h * 64 + scol;
    const u16* Vg = Vt + ((size_t)(n * 1024 + h * 64 + wave * 16 + srow)) * SEQ + scol;
    u16* KsD0 = &Ks[0][wave * 512];
    u16* KsD1 = &Ks[1][wave * 512];
    u16* VsD0 = &Vs[0][wave * 512];
    u16* VsD1 = &Vs[1][wave * 512];

    f32x4 o[2][4] = {};
    float l_acc[2] = {0.f, 0.f};
    const int nch = 2 * qb + 2;

    for (int c = 0; c < nch; ++c) {
        const int kv0 = c * 64;
        const size_t krow = (size_t)kv0 * DM;
        GLD16(Kg + krow, KsD0);
        GLD16(Kg + krow + 32, KsD1);
        GLD16(Vg + kv0, VsD0);
        GLD16(Vg + kv0 + 32, VsD1);
        __syncthreads();

        bf16x8 a[4][2];
#pragma unroll
        for (int mt = 0; mt < 4; ++mt) {
            a[mt][0] = ld8(&Ks[0][(mt * 16 + l4) * 32 + q4 * 8]);
            a[mt][1] = ld8(&Ks[1][(mt * 16 + l4) * 32 + q4 * 8]);
        }
#pragma unroll
        for (int qt = 0; qt < 2; ++qt) {
            f32x4 st[4];
#pragma unroll
            for (int mt = 0; mt < 4; ++mt) {
                f32x4 zz = {0.f, 0.f, 0.f, 0.f};
                st[mt] = __builtin_amdgcn_mfma_f32_16x16x32_bf16(a[mt][0], qf[qt][0], zz, 0, 0, 0);
                st[mt] = __builtin_amdgcn_mfma_f32_16x16x32_bf16(a[mt][1], qf[qt][1], st[mt], 0, 0, 0);
            }
            const int qg = Q0w + qt * 16 + l4;
            u16* P = Pl[wave][qt];
            float la = l_acc[qt];
#pragma unroll
            for (int mt = 0; mt < 4; ++mt) {
                __bf16 pk[4];
#pragma unroll
                for (int r = 0; r < 4; ++r) {
                    const int kv = kv0 + mt * 16 + q4 * 4 + r;
                    float p = __builtin_amdgcn_exp2f(st[mt][r]);
                    p = (kv > qg) ? 0.f : p;
                    la += p;
                    pk[r] = (__bf16)p;
                }
                *(u16x4*)(P + l4 * 72 + mt * 16 + q4 * 4) = *(u16x4*)pk;
            }
            l_acc[qt] = la;
        }
#pragma unroll
        for (int ks = 0; ks < 2; ++ks) {
            bf16x8 pf0 = ld8(&Pl[wave][0][l4 * 72 + ks * 32 + q4 * 8]);
            bf16x8 pf1 = ld8(&Pl[wave][1][l4 * 72 + ks * 32 + q4 * 8]);
#pragma unroll
            for (int nt = 0; nt < 4; ++nt) {
                bf16x8 vf = ld8(&Vs[ks][(nt * 16 + l4) * 32 + q4 * 8]);
                o[0][nt] = __builtin_amdgcn_mfma_f32_16x16x32_bf16(pf0, vf, o[0][nt], 0, 0, 0);
                o[1][nt] = __builtin_amdgcn_mfma_f32_16x16x32_bf16(pf1, vf, o[1][nt], 0, 0, 0);
            }
        }
        __syncthreads();
    }

#pragma unroll
    for (int qt = 0; qt < 2; ++qt) {
        float l = l_acc[qt];
        l += __shfl_xor(l, 16);
        l += __shfl_xor(l, 32);
        float lr[4];
#pragma unroll
        for (int r = 0; r < 4; ++r) lr[r] = 1.f / __shfl(l, q4 * 4 + r);
#pragma unroll
        for (int nt = 0; nt < 4; ++nt) {
            const int col = h * 64 + nt * 16 + l4;
#pragma unroll
            for (int r = 0; r < 4; ++r) {
                const int row = n * SEQ + Q0w + qt * 16 + q4 * 4 + r;
                Z[(size_t)row * DM + col] = f2bf(o[qt][nt][r] * lr[r]);
            }
        }
    }
}

extern "C" void kernel_launch(void* const* d_in, const int* in_sizes, int n_in,
                              void* d_out, int out_size, void* d_ws, size_t ws_size,
                              hipStream_t stream) {
    const void* x  = d_in[0];
    const void* Wq = d_in[1];
    const void* bq = d_in[2];
    const void* Wk = d_in[3];
    const void* bk = d_in[4];
    const void* Wv = d_in[5];
    const void* bv = d_in[6];
    const void* Wo = d_in[7];
    const void* bo = d_in[8];
    const void* g  = d_in[9];
    const void* b  = d_in[10];
    u16* ws = (u16*)d_ws;

    u16* xn  = ws;
    u16* Qb  = ws + (size_t)TOKS;
    u16* Kb  = ws + (size_t)2 * TOKS;
    u16* Vtb = ws + (size_t)3 * TOKS;
    u16* Zb  = ws;  // xn dead after qkv gemm
    u16* Wc  = ws + (size_t)4 * TOKS;
    u16* Vc  = Wc + 4 * 1048576;
    int* flagp = (int*)(Vc + 8 * 1024);

    detect_k<<<dim3(1), 64, 0, stream>>>((const u32*)x, flagp);
    convert_k<<<dim3(1024, 5), 256, 0, stream>>>(Wq, Wk, Wv, Wo, bq, bk, bv, bo, g, b, Wc, Vc, flagp);
    ln_k<<<dim3(4 * SEQ), 256, 0, stream>>>(x, Vc + 4 * 1024, Vc + 5 * 1024, xn, flagp);
    gemm_qkv_k<<<dim3(32, 12), 512, 0, stream>>>(xn, Wc, Vc, Qb, Kb, Vtb);
    flash_k<<<dim3(64, 16), 256, 0, stream>>>(Qb, Kb, Vtb, Zb);
    gemm_out_k<<<dim3(32, 8), 512, 0, stream>>>(Zb, Wc, Vc, (u16*)d_out, flagp);
}